// Round 14
// baseline (61.749 us; speedup 1.0000x reference)
//
#include <hip/hip_runtime.h>

#define NQ 4
#define NL 2
#define NA 16
#define HDIM 256
#define BLK 64    // 1 wave per block
#define RPB 64    // rows per block -> 4096 blocks at B=262144

__device__ __forceinline__ float dot4(float4 a, float4 b) {
    return fmaf(a.x, b.x, fmaf(a.y, b.y, fmaf(a.z, b.z, a.w * b.w)));
}

// 1-qubit gate, qubit mask M. u = {u00r,u00i,u01r,u01i,u10r,u10i,u11r,u11i}
template<int M>
__device__ __forceinline__ void apply_u(float* sr, float* si, const float* u) {
    const float u00r = u[0], u00i = u[1], u01r = u[2], u01i = u[3];
    const float u10r = u[4], u10i = u[5], u11r = u[6], u11i = u[7];
#pragma unroll
    for (int k = 0; k < 16; ++k) {
        if (k & M) continue;
        const int k1 = k | M;
        const float a0r = sr[k],  a0i = si[k];
        const float a1r = sr[k1], a1i = si[k1];
        sr[k]  = u00r*a0r - u00i*a0i + u01r*a1r - u01i*a1i;
        si[k]  = u00r*a0i + u00i*a0r + u01r*a1i + u01i*a1r;
        sr[k1] = u10r*a0r - u10i*a0i + u11r*a1r - u11i*a1i;
        si[k1] = u10r*a0i + u10i*a0r + u11r*a1i + u11i*a1r;
    }
}

template<int MC, int MT>
__device__ __forceinline__ void cnot(float* sr, float* si) {
#pragma unroll
    for (int k = 0; k < 16; ++k) {
        if ((k & MC) && !(k & MT)) {
            const int k1 = k | MT;
            float tr = sr[k]; sr[k] = sr[k1]; sr[k1] = tr;
            float ti = si[k]; si[k] = si[k1]; si[k1] = ti;
        }
    }
}

__global__ __launch_bounds__(BLK) void qph_kernel(
    const float* __restrict__ h,
    const float* __restrict__ W_embed,
    const float* __restrict__ b_embed,
    const float* __restrict__ q_weights,
    const float* __restrict__ W_out,
    const float* __restrict__ b_out,
    float* __restrict__ out,
    int B)
{
    __shared__ float rot_lds[NL * NQ][8];
    __shared__ float wout_lds[NA * NQ];
    __shared__ float bout_lds[NA];
    __shared__ __align__(16) float tbuf[RPB * 4];   // 1 KB 4x4-transpose buffer

    const int l = threadIdx.x;   // lane 0..63
    const int t = l & 3;
    const int g = l >> 2;        // 4-lane group 0..15
    const long rowBase = (long)blockIdx.x * RPB;

    // ---- stage tiny shared data ----
    if (l < NA * NQ) wout_lds[l] = W_out[l];
    if (l < NA)      bout_lds[l] = b_out[l];
    if (l < NL * NQ) {
        // Rot(phi,theta,omega) = RZ(omega) RY(theta) RZ(phi)
        const float phi = q_weights[l * 3 + 0];
        const float th  = q_weights[l * 3 + 1];
        const float om  = q_weights[l * 3 + 2];
        const float c  = cosf(0.5f * th), s  = sinf(0.5f * th);
        const float al = 0.5f * (phi + om), be = 0.5f * (phi - om);
        const float ca = cosf(al), sa = sinf(al);
        const float cb = cosf(be), sb = sinf(be);
        rot_lds[l][0] =  ca * c;  rot_lds[l][1] = -sa * c;   // u00
        rot_lds[l][2] = -cb * s;  rot_lds[l][3] = -sb * s;   // u01
        rot_lds[l][4] =  cb * s;  rot_lds[l][5] = -sb * s;   // u10
        rot_lds[l][6] =  ca * c;  rot_lds[l][7] =  sa * c;   // u11
    }

    // ---- W_embed -> 16 VGPRs: lane l owns columns 4l..4l+3 for all 4 q ----
    float4 wq0 = *(const float4*)(W_embed + 0 * HDIM + 4 * l);
    float4 wq1 = *(const float4*)(W_embed + 1 * HDIM + 4 * l);
    float4 wq2 = *(const float4*)(W_embed + 2 * HDIM + 4 * l);
    float4 wq3 = *(const float4*)(W_embed + 3 * HDIM + 4 * l);
    __syncthreads();

    // ---- phase 1: 64 rows, each load instruction reads ONE row contiguously
    // (lane l -> bytes 16l..16l+15 of the row: 1 KB/wave-instruction).
    float keep0 = 0.f, keep1 = 0.f, keep2 = 0.f, keep3 = 0.f;
    const float4* __restrict__ h4 = (const float4*)h;

#pragma unroll
    for (int it = 0; it < RPB; ++it) {
        long ro = rowBase + it; if (ro >= B) ro = B - 1;
        const float4 hv = h4[ro * 64 + l];

        const float p0 = dot4(hv, wq0);
        const float p1 = dot4(hv, wq1);
        const float p2 = dot4(hv, wq2);
        const float p3 = dot4(hv, wq3);

        // stage A: combine-exchange within the 4-lane group ->
        // lane ends with the group's partial of q = l&3
        float a01 = (l & 1) ? p1 : p0;
        float b01 = (l & 1) ? p0 : p1;
        a01 += __shfl_xor(b01, 1);
        float a23 = (l & 1) ? p3 : p2;
        float b23 = (l & 1) ? p2 : p3;
        a23 += __shfl_xor(b23, 1);
        float aa = (l & 2) ? a23 : a01;
        float bb = (l & 2) ? a01 : a23;
        aa += __shfl_xor(bb, 2);
        // stage B: sum the 16 groups
        aa += __shfl_xor(aa, 4);
        aa += __shfl_xor(aa, 8);
        aa += __shfl_xor(aa, 16);
        aa += __shfl_xor(aa, 32);
        // lane l keeps rows 4g..4g+3 (q = l&3 each)
        if ((it >> 2) == g) {
            if ((it & 3) == 0) keep0 = aa;
            if ((it & 3) == 1) keep1 = aa;
            if ((it & 3) == 2) keep2 = aa;
            if ((it & 3) == 3) keep3 = aa;
        }
    }

    // ---- 4x4 transpose via LDS: lane l gets its OWN row's 4 q-sums ----
    tbuf[(g * 4 + 0) * 4 + t] = keep0;
    tbuf[(g * 4 + 1) * 4 + t] = keep1;
    tbuf[(g * 4 + 2) * 4 + t] = keep2;
    tbuf[(g * 4 + 3) * 4 + t] = keep3;
    __syncthreads();
    const float4 sv = *(const float4*)&tbuf[l * 4];

    // ---- phase 2: this thread owns row rowBase + l ----
    const long grow = rowBase + l;
    if (grow >= B) return;

    const float angs[4] = {tanhf(sv.x + b_embed[0]), tanhf(sv.y + b_embed[1]),
                           tanhf(sv.z + b_embed[2]), tanhf(sv.w + b_embed[3])};

    float sr[16], si[16];
#pragma unroll
    for (int k = 0; k < 16; ++k) { sr[k] = 0.f; si[k] = 0.f; }
    sr[0] = 1.0f;

    // AngleEmbedding: RX(theta_q)
#pragma unroll
    for (int q = 0; q < NQ; ++q) {
        const float th = angs[q];
        const float c = __cosf(0.5f * th), s = __sinf(0.5f * th);
        const int m = 8 >> q;
#pragma unroll
        for (int k = 0; k < 16; ++k) {
            if (k & m) continue;
            const int k1 = k | m;
            const float a0r = sr[k],  a0i = si[k];
            const float a1r = sr[k1], a1i = si[k1];
            sr[k]  = c * a0r + s * a1i;
            si[k]  = c * a0i - s * a1r;
            sr[k1] = s * a0i + c * a1r;
            si[k1] = c * a1i - s * a0r;
        }
    }

    // StronglyEntanglingLayers
    apply_u<8>(sr, si, rot_lds[0]);
    apply_u<4>(sr, si, rot_lds[1]);
    apply_u<2>(sr, si, rot_lds[2]);
    apply_u<1>(sr, si, rot_lds[3]);
    cnot<8, 4>(sr, si);
    cnot<4, 2>(sr, si);
    cnot<2, 1>(sr, si);
    cnot<1, 8>(sr, si);
    apply_u<8>(sr, si, rot_lds[4]);
    apply_u<4>(sr, si, rot_lds[5]);
    apply_u<2>(sr, si, rot_lds[6]);
    apply_u<1>(sr, si, rot_lds[7]);
    cnot<8, 2>(sr, si);
    cnot<4, 1>(sr, si);
    cnot<2, 8>(sr, si);
    cnot<1, 4>(sr, si);

    // PauliZ expectations
    float p[16];
#pragma unroll
    for (int k = 0; k < 16; ++k) p[k] = sr[k] * sr[k] + si[k] * si[k];
    float z[4];
#pragma unroll
    for (int q = 0; q < NQ; ++q) {
        const int m = 8 >> q;
        float zz = 0.f;
#pragma unroll
        for (int k = 0; k < 16; ++k) zz += (k & m) ? -p[k] : p[k];
        z[q] = zz;
    }

    // out = z @ W_out^T + b_out
    float4* out4 = (float4*)(out + grow * (long)NA);
#pragma unroll
    for (int i = 0; i < 4; ++i) {
        float o[4];
#pragma unroll
        for (int jj = 0; jj < 4; ++jj) {
            const int a = i * 4 + jj;
            float v = bout_lds[a];
#pragma unroll
            for (int q = 0; q < NQ; ++q) v = fmaf(z[q], wout_lds[a * 4 + q], v);
            o[jj] = v;
        }
        out4[i] = make_float4(o[0], o[1], o[2], o[3]);
    }
}

extern "C" void kernel_launch(void* const* d_in, const int* in_sizes, int n_in,
                              void* d_out, int out_size, void* d_ws, size_t ws_size,
                              hipStream_t stream) {
    const float* h         = (const float*)d_in[0];
    const float* W_embed   = (const float*)d_in[1];
    const float* b_embed   = (const float*)d_in[2];
    const float* q_weights = (const float*)d_in[3];
    const float* W_out     = (const float*)d_in[4];
    const float* b_out     = (const float*)d_in[5];
    float* out = (float*)d_out;

    const int B = in_sizes[0] / HDIM;
    const int blocks = (B + RPB - 1) / RPB;
    qph_kernel<<<blocks, BLK, 0, stream>>>(h, W_embed, b_embed, q_weights, W_out, b_out, out, B);
}